// Round 5
// baseline (456.074 us; speedup 1.0000x reference)
//
#include <hip/hip_runtime.h>
#include <stdint.h>

#define DEVI __device__ __forceinline__

using bf16x8 = __attribute__((ext_vector_type(8))) __bf16;
using f32x4  = __attribute__((ext_vector_type(4))) float;

DEVI ushort f2bf(float f){
  uint32_t u = __float_as_uint(f);
  uint32_t r = u + 0x7fffu + ((u >> 16) & 1u);   // RNE
  return (ushort)(r >> 16);
}
DEVI float bf2f(ushort h){ return __uint_as_float(((uint32_t)h) << 16); }

// async 16B global -> LDS (wave-uniform LDS base; lane lands at base + lane*16)
DEVI void async16(const ushort* g, ushort* l, int lbyte) {
  __builtin_amdgcn_global_load_lds(
      (const __attribute__((address_space(1))) uint32_t*)g,
      (__attribute__((address_space(3))) uint32_t*)((char*)l + lbyte),
      16, 0, 0);
}

// ---------------------------------------------------------------------------
// Segmented mega kernel. Paths:
//  flags&128: FUSED GCN LAYER  out = relu(G @ (X @ Wslab)) [+ dual branch]
//             block = (z, 32-col slab), grid 1024/layer. N=32 (was 64) so:
//               * acc[4][2]=32 + pk=16 regs -> no scratch spill (R1/R4 had
//                 a 32-reg pk spill: +17MB symmetric FETCH/WRITE)
//               * LDS 53760 B -> 3 blocks/CU (12 waves) -> block phases
//                 interleave, MFMA pipe fed during other blocks' stalls
//             phase1 Y(256x32)=X@Wslab -> LDS transposed; phase2 G@Y.
//             Staging dbuf, prefetch-after-barrier. Dual branch straight-lined.
//  flags&64 : fused Sc + row softmax (LDS-staged, pipelined)
//  else     : plain NT GEMM 128x128 tile, LDS-staged, double-buffered
// flags: 1=relu 2=out_bf16 4=add Src2 bf16 16=dual 64=ScS 128=fused layer
// ---------------------------------------------------------------------------
struct Seg {
  const ushort* A; const ushort* B; const void* Src; const void* Src2; void* O;
  long long sA, sB, sS, sS2, sO;
  int lda, ldb, ldS, ldS2, ldc;
  int K, nbx, nbxy, flags;
  long long A2off, B2off;
};

__global__ __launch_bounds__(256, 2)
void mega(Seg s0, Seg s1, Seg s2, int n0s, int n01)
{
  extern __shared__ __align__(16) ushort lds[];
  int bid = blockIdx.x;
  const Seg& s = (bid < n0s) ? s0 : ((bid < n01) ? s1 : s2);
  if (bid >= n0s) bid -= (bid < n01) ? n0s : n01;

  const int t = threadIdx.x;
  const int lane = t & 63, wave = t >> 6;
  const int lr = lane & 15, lq = lane >> 4;
  const int lb0 = __builtin_amdgcn_readfirstlane((t & 192) * 16);

#define MFMA16(Aa, Bb) { _Pragma("unroll") for (int x = 0; x < 4; x++)           \
    _Pragma("unroll") for (int y = 0; y < 4; y++)                                \
      acc[x][y] = __builtin_amdgcn_mfma_f32_16x16x32_bf16(Aa[x], Bb[y], acc[x][y], 0, 0, 0); }

#define MFMA42(Aa, Bb) { _Pragma("unroll") for (int x = 0; x < 4; x++)           \
    _Pragma("unroll") for (int y = 0; y < 2; y++)                                \
      acc[x][y] = __builtin_amdgcn_mfma_f32_16x16x32_bf16(Aa[x], Bb[y], acc[x][y], 0, 0, 0); }

  if (s.flags & 128) {
    // ================= fused GCN layer (N=32 slab) =================
    const int z    = (bid & 7) + ((bid >> 7) << 3);   // XCD swizzle: same z -> same XCD
    const int slab = (bid >> 3) & 15;
    const int n0   = slab * 32;

    // LDS map (bytes):
    //   [0, 16896)              Yt: 32 cols x 264 (256 rows + pad), bf16
    //   [16896 + b*18432, ...)  staging buf b: stA 256x32 (16384B) + stW 32x32 (2048B)
    ushort* Yt = lds;

    const int r0 = t >> 2, c0 = (t & 3) * 8;

    const ushort* X  = s.A + (long long)z * s.sA;
    const ushort* Wf = s.B + (long long)n0 * 512;
    const ushort* G0 = (const ushort*)s.Src + (long long)z * s.sS;

    f32x4 acc[4][2] = {};

#define COMPUTE1(curb) {                                                         \
      const ushort* sA = (const ushort*)((const char*)lds + 16896 + (curb)*18432); \
      const ushort* sW = sA + 8192;    /* +16384 B */                            \
      bf16x8 af[4], bw[2];                                                       \
      _Pragma("unroll") for (int x = 0; x < 4; x++)                              \
        af[x] = *(const bf16x8*)&sA[(64*wave + x*16 + lr)*32 + lq*8];            \
      _Pragma("unroll") for (int y = 0; y < 2; y++)                              \
        bw[y] = *(const bf16x8*)&sW[(y*16 + lr)*32 + lq*8];                      \
      MFMA42(af, bw); }

#define COMPUTE2(curb, kk) {                                                     \
      const ushort* sA = (const ushort*)((const char*)lds + 16896 + (curb)*18432); \
      bf16x8 af[4], bfr[2];                                                      \
      _Pragma("unroll") for (int x = 0; x < 4; x++)                              \
        af[x] = *(const bf16x8*)&sA[(64*wave + x*16 + lr)*32 + lq*8];            \
      _Pragma("unroll") for (int y = 0; y < 2; y++)                              \
        bfr[y] = *(const bf16x8*)&Yt[(y*16 + lr)*264 + (kk) + lq*8];             \
      MFMA42(af, bfr); }

#define ISSUE1(k0s, b) { const int _o = 16896 + (b)*18432 + lb0;                 \
      _Pragma("unroll") for (int i = 0; i < 4; i++)                              \
        async16(pX + (long long)(64*i)*512 + (k0s), lds, _o + i*4096);           \
      if (t < 128) async16(pW + (k0s), lds, _o + 16384); }

#define ISSUE2(k0s, b) { const int _o = 16896 + (b)*18432 + lb0;                 \
      _Pragma("unroll") for (int i = 0; i < 4; i++)                              \
        async16(pG + (long long)(64*i)*s.ldS + (k0s), lds, _o + i*4096); }

    // one full (ph1 -> Yt -> ph2) pass; result accumulates into acc
#define PASS(Wptr, Gptr) {                                                       \
      const ushort* pX = X + (long long)r0*512 + c0;                             \
      const ushort* pW = (Wptr) + (long long)r0*512 + c0;  /* r0<32 when t<128 */\
      __syncthreads();                 /* prior staging/Yt reads complete */     \
      ISSUE1(0, 0);                                                              \
      for (int k0 = 0; k0 < 480; k0 += 32) {                                     \
        const int cur = (k0 >> 5) & 1;                                           \
        __syncthreads();               /* buf cur ready */                       \
        ISSUE1(k0 + 32, cur ^ 1);      /* flies under MFMA below */              \
        COMPUTE1(cur);                                                           \
      }                                                                          \
      __syncthreads();                                                           \
      COMPUTE1(1);                     /* k0=480 landed in buf 1 */              \
      _Pragma("unroll") for (int x = 0; x < 4; x++)                              \
        _Pragma("unroll") for (int y = 0; y < 2; y++) {                          \
          const int col  = y*16 + lr;                                            \
          const int rowb = 64*wave + x*16 + lq*4;                                \
          uint2 vv;                                                              \
          vv.x = (uint)f2bf(acc[x][y][0]) | ((uint)f2bf(acc[x][y][1]) << 16);    \
          vv.y = (uint)f2bf(acc[x][y][2]) | ((uint)f2bf(acc[x][y][3]) << 16);    \
          *(uint2*)&Yt[col*264 + rowb] = vv;                                     \
          acc[x][y] = (f32x4){0.f, 0.f, 0.f, 0.f};                               \
        }                                                                        \
      const ushort* pG = (Gptr) + (long long)r0 * s.ldS + c0;                    \
      __syncthreads();                 /* Yt visible; ph1 stA reads done */      \
      ISSUE2(0, 0);                                                              \
      for (int k0 = 0; k0 < 224; k0 += 32) {                                     \
        const int cur = (k0 >> 5) & 1;                                           \
        __syncthreads();                                                         \
        ISSUE2(k0 + 32, cur ^ 1);                                                \
        COMPUTE2(cur, k0);                                                       \
      }                                                                          \
      __syncthreads();                                                           \
      COMPUTE2(1, 224);                                                          \
    }

#define EPILOG(PKADD) {                                                          \
      const int fl = s.flags;                                                    \
      _Pragma("unroll") for (int x = 0; x < 4; x++)                              \
        _Pragma("unroll") for (int y = 0; y < 2; y++) {                          \
          const int col = n0 + y*16 + lr;                                        \
          _Pragma("unroll") for (int r = 0; r < 4; r++) {                        \
            const int row = 64*wave + x*16 + lq*4 + r;                           \
            float v = fmaxf(acc[x][y][r], 0.f);                                  \
            PKADD;                                                               \
            if (fl & 4)  v += bf2f(((const ushort*)s.Src2)[(long long)z*s.sS2 + (long long)row*s.ldS2 + col]); \
            if (fl & 2)                                                          \
              ((ushort*)s.O)[(long long)z*s.sO + (long long)row*s.ldc + col] = f2bf(v); \
            else                                                                 \
              ((float*)s.O)[(long long)z*s.sO + (long long)row*s.ldc + col] = v; \
          } } }

    if (s.flags & 16) {
      // -------- dual branch, straight-lined --------
      uint pk[4][2][2];
      PASS(Wf, G0);
      #pragma unroll
      for (int x = 0; x < 4; x++)
        #pragma unroll
        for (int y = 0; y < 2; y++) {
          pk[x][y][0] = (uint)f2bf(fmaxf(acc[x][y][0],0.f)) | ((uint)f2bf(fmaxf(acc[x][y][1],0.f)) << 16);
          pk[x][y][1] = (uint)f2bf(fmaxf(acc[x][y][2],0.f)) | ((uint)f2bf(fmaxf(acc[x][y][3],0.f)) << 16);
          acc[x][y] = (f32x4){0.f, 0.f, 0.f, 0.f};
        }
      PASS(Wf + s.B2off, G0 + s.A2off);
      EPILOG(v += bf2f((ushort)(pk[x][y][r >> 1] >> (16*(r & 1)))));
    } else {
      // -------- single branch --------
      PASS(Wf, G0);
      EPILOG(;);
    }
    return;
  }

  if (s.flags & 64) {
    // ================= fused Sc + row softmax =================
    const int niter = s.K >> 5;
    const int z = bid >> 2, mb = bid & 3;
    const ushort* pa = s.A + (long long)z*s.sA + (long long)(mb*64 + (t >> 2))*s.lda + (t & 3)*8;
    const ushort* pb = s.B + (long long)z*s.sB + (long long)(t >> 2)*s.ldb + (t & 3)*8;
    const long long b64 = 64ll*s.ldb;

    f32x4 acc[16] = {};
#define ISSUE_S(idx) { const int _i=(idx); const int _o=(_i&1)*20480 + lb0;      \
    const int _k=_i<<5;                                                          \
    async16(pa + _k, lds, _o);                                                   \
    async16(pb + _k,        lds, _o + 4096);                                     \
    async16(pb + b64 + _k,  lds, _o + 8192);                                     \
    async16(pb + 2*b64 + _k,lds, _o + 12288);                                    \
    async16(pb + 3*b64 + _k,lds, _o + 16384); }
    ISSUE_S(0);
    for (int i = 0; i < niter; ++i) {
      __syncthreads();
      if (i + 1 < niter) ISSUE_S(i + 1);
      const ushort* LA = lds + (i & 1)*10240;
      const ushort* LB = LA + 2048;
      const bf16x8 af = *(const bf16x8*)&LA[(wave*16 + lr)*32 + lq*8];
      #pragma unroll
      for (int j = 0; j < 16; j++) {
        const bf16x8 bfr = *(const bf16x8*)&LB[(j*16 + lr)*32 + lq*8];
        acc[j] = __builtin_amdgcn_mfma_f32_16x16x32_bf16(af, bfr, acc[j], 0, 0, 0);
      }
    }
    float mx[4] = {-1e30f, -1e30f, -1e30f, -1e30f};
    #pragma unroll
    for (int j = 0; j < 16; j++)
      #pragma unroll
      for (int r = 0; r < 4; r++) mx[r] = fmaxf(mx[r], acc[j][r]);
    #pragma unroll
    for (int r = 0; r < 4; r++)
      #pragma unroll
      for (int off = 1; off <= 8; off <<= 1) mx[r] = fmaxf(mx[r], __shfl_xor(mx[r], off, 64));
    float sm[4] = {0.f, 0.f, 0.f, 0.f};
    #pragma unroll
    for (int j = 0; j < 16; j++)
      #pragma unroll
      for (int r = 0; r < 4; r++) { float e = __expf(acc[j][r] - mx[r]); acc[j][r] = e; sm[r] += e; }
    #pragma unroll
    for (int r = 0; r < 4; r++) {
      #pragma unroll
      for (int off = 1; off <= 8; off <<= 1) sm[r] += __shfl_xor(sm[r], off, 64);
      sm[r] = 1.0f / sm[r];
    }
    ushort* Oz = (ushort*)s.O + (long long)z*s.sO;
    #pragma unroll
    for (int j = 0; j < 16; j++)
      #pragma unroll
      for (int r = 0; r < 4; r++) {
        const int row = mb*64 + wave*16 + lq*4 + r;
        Oz[(long long)row*s.ldc + j*16 + lr] = f2bf(acc[j][r]*sm[r]);
      }
    return;
  }

  // ================= plain NT GEMM, double-buffered =================
  {
    // buf b (bytes): lA 128x32 at b*16384, lB 128x32 at b*16384 + 8192
    const int z  = bid / s.nbxy;
    const int rz = bid % s.nbxy;
    const int bx = rz % s.nbx, by = rz / s.nbx;
    const int wm = (wave >> 1)*64, wn = (wave & 1)*64;
    const int r0 = t >> 2, c0 = (t & 3)*8;

    const ushort* pa = s.A + (long long)z*s.sA + (long long)(by*128 + r0)*s.lda + c0;
    const ushort* pb = s.B + (long long)z*s.sB + (long long)(bx*128 + r0)*s.ldb + c0;
    const long long a64 = 64ll*s.lda, b64 = 64ll*s.ldb;

#define ISSUEP(k0s, b) { const int _o = (b)*16384 + lb0;                         \
      async16(pa + (k0s),       lds, _o);                                        \
      async16(pa + a64 + (k0s), lds, _o + 4096);                                 \
      async16(pb + (k0s),       lds, _o + 8192);                                 \
      async16(pb + b64 + (k0s), lds, _o + 12288); }

#define COMPUTEP(curb) {                                                         \
      const ushort* lA = (const ushort*)((const char*)lds + (curb)*16384);       \
      const ushort* lB = lA + 4096;                                              \
      bf16x8 af[4], bfr[4];                                                      \
      _Pragma("unroll") for (int x = 0; x < 4; x++) {                            \
        af[x]  = *(const bf16x8*)&lA[(wm + x*16 + lr)*32 + lq*8];                \
        bfr[x] = *(const bf16x8*)&lB[(wn + x*16 + lr)*32 + lq*8];                \
      }                                                                          \
      MFMA16(af, bfr); }

    f32x4 acc[4][4] = {};
    ISSUEP(0, 0);
    int k0 = 0;
    for (; k0 < s.K - 32; k0 += 32) {
      const int cur = (k0 >> 5) & 1;
      __syncthreads();                 // buf cur ready
      ISSUEP(k0 + 32, cur ^ 1);
      COMPUTEP(cur);
    }
    __syncthreads();
    COMPUTEP((k0 >> 5) & 1);
    const int rowb = by*128 + wm + lq*4;
    const int colb = bx*128 + wn + lr;
    const int fl = s.flags;
    #pragma unroll
    for (int x = 0; x < 4; x++)
      #pragma unroll
      for (int y = 0; y < 4; y++) {
        const int col = colb + y*16;
        #pragma unroll
        for (int r = 0; r < 4; r++) {
          const int row = rowb + x*16 + r;
          float v = acc[x][y][r];
          if (fl & 1) v = fmaxf(v, 0.f);
          if (fl & 2)
            ((ushort*)s.O)[(long long)z*s.sO + (long long)row*s.ldc + col] = f2bf(v);
          else
            ((float*)s.O)[(long long)z*s.sO + (long long)row*s.ldc + col] = v;
        }
      }
  }
}

// ---------------------------------------------------------------------------
// fused prep: [0,8192) cast f -> bf16 ; [8192,11008) 11 weight transposes ;
// [11008,15104) adj -> adj/adjT bf16
// ---------------------------------------------------------------------------
struct P11 { const float* p[11]; };

__global__ void prep(const float* __restrict__ F, ushort* __restrict__ FB,
                     P11 ps, ushort* __restrict__ WT,
                     const float* __restrict__ ADJ, ushort* __restrict__ AB,
                     ushort* __restrict__ ATB)
{
  __shared__ float tile[32][33];
  const int b = blockIdx.x, t = threadIdx.x;
  if (b < 8192) {
    const int i = b*256 + t;
    const float4 v = ((const float4*)F)[i];
    ushort4 o; o.x = f2bf(v.x); o.y = f2bf(v.y); o.z = f2bf(v.z); o.w = f2bf(v.w);
    ((ushort4*)FB)[i] = o;
  } else if (b < 11008) {
    const int q = b - 8192;
    const int wdx = q >> 8, tl = q & 255;
    const int bo = (tl & 15)*32, bk = (tl >> 4)*32;
    const int tx = t & 31, ty = t >> 5;
    const float* in = ps.p[wdx];
    ushort* o = WT + (long long)wdx*262144;
    #pragma unroll
    for (int r = 0; r < 32; r += 8) tile[ty+r][tx] = in[(long long)(bk+ty+r)*512 + bo+tx];
    __syncthreads();
    #pragma unroll
    for (int r = 0; r < 32; r += 8) o[(long long)(bo+ty+r)*512 + bk+tx] = f2bf(tile[tx][ty+r]);
  } else {
    const int q = b - 11008;
    const long long base = (long long)(q >> 6)*65536;
    const int bi = ((q >> 3) & 7)*32, bj = (q & 7)*32;
    const int tx = t & 31, ty = t >> 5;
    #pragma unroll
    for (int r = 0; r < 32; r += 8) {
      const float v = ADJ[base + (long long)(bi+ty+r)*256 + bj+tx];
      tile[ty+r][tx] = v;
      AB[base + (long long)(bi+ty+r)*256 + bj+tx] = f2bf(v);
    }
    __syncthreads();
    #pragma unroll
    for (int r = 0; r < 32; r += 8)
      ATB[base + (long long)(bj+ty+r)*256 + bi+tx] = f2bf(tile[tx][ty+r]);
  }
}

// ---------------------------------------------------------------------------
extern "C" void kernel_launch(void* const* d_in, const int* in_sizes, int n_in,
                              void* d_out, int out_size, void* d_ws, size_t ws_size,
                              hipStream_t stream)
{
  (void)in_sizes; (void)n_in; (void)out_size;
  const float* F   = (const float*)d_in[0];
  const float* ADJ = (const float*)d_in[2];

  uint8_t* w = (uint8_t*)d_ws;
  size_t off = 0;
  auto alloc = [&](size_t bytes) -> void* { void* p = w + off; off += (bytes + 255) & ~(size_t)255; return p; };

  const long long SL = 262144;
  ushort* WT   = (ushort*)alloc(11*524288);  // 0:Wst1 1:Wst1b 2:Wst2 3:Wst2b 4:Wst3 5:Wst3b 6-8:Wsim1-3 9:Wse1T 10:Wse2T
  ushort* WMT  = (ushort*)alloc(524288);
  ushort* FB   = (ushort*)alloc(16777216);
  ushort* ADJB = (ushort*)alloc(8388608);
  ushort* ADJT = (ushort*)alloc(8388608);
  ushort* TB   = (ushort*)alloc(16777216);
  ushort* Sb   = (ushort*)alloc(8388608);
  ushort* Hb   = (ushort*)alloc(16777216);   // st ping
  ushort* Hb2  = (ushort*)alloc(16777216);   // st pong
  ushort* Gb   = (ushort*)alloc(16777216);   // sim ping
  ushort* Gb2  = (ushort*)alloc(16777216);   // sim pong
  if (off > ws_size) return;

  const long long sNC = 131072, sNN = 65536;
  const int LDSB = 53760;   // Yt 16896 + 2x(16384+2048) staging dbuf -> 3 blocks/CU

  auto zero = [](Seg& s) {
    s.A = nullptr; s.B = nullptr; s.Src = nullptr; s.Src2 = nullptr; s.O = nullptr;
    s.sA = s.sB = s.sS = s.sS2 = s.sO = 0;
    s.lda = s.ldb = s.ldS = s.ldS2 = s.ldc = 0;
    s.K = 0; s.nbx = 1; s.nbxy = 1; s.flags = 0; s.A2off = s.B2off = 0;
  };
  auto mkP = [&](const void* A, long long sA, int lda, const void* B, long long sB, int ldb,
                 void* O, long long sO, int ldc, int K, int M, int Nn, int flags) -> Seg {
    Seg s; zero(s);
    s.A = (const ushort*)A; s.B = (const ushort*)B; s.O = O;
    s.sA = sA; s.sB = sB; s.sO = sO;
    s.lda = lda; s.ldb = ldb; s.ldc = ldc;
    s.K = K; s.nbx = Nn/128; s.nbxy = (Nn/128)*(M/128); s.flags = flags;
    return s;
  };
  auto mkF = [&](const void* X, const void* Wf, long long B2off, const void* G, long long A2off,
                 const void* Src2, void* O, int flags) -> Seg {
    Seg s; zero(s);
    s.A = (const ushort*)X; s.sA = sNC; s.lda = 512;
    s.B = (const ushort*)Wf; s.B2off = B2off;
    s.Src = G; s.sS = sNN; s.ldS = 256; s.A2off = A2off;
    s.Src2 = Src2; s.sS2 = sNC; s.ldS2 = 512;
    s.O = O; s.sO = sNC; s.ldc = 512;
    s.flags = 128 | flags;
    return s;
  };
  auto L1 = [&](const Seg& a, int na) { mega<<<na, 256, LDSB, stream>>>(a, a, a, na, na); };
  auto L2 = [&](const Seg& a, int na, const Seg& b, int nb) {
    mega<<<na+nb, 256, LDSB, stream>>>(a, b, b, na, na+nb); };

  // ---- D1: fused prep ----
  P11 ps;
  ps.p[0] = (const float*)d_in[5];  ps.p[1] = (const float*)d_in[8];
  ps.p[2] = (const float*)d_in[6];  ps.p[3] = (const float*)d_in[9];
  ps.p[4] = (const float*)d_in[7];  ps.p[5] = (const float*)d_in[10];
  ps.p[6] = (const float*)d_in[11]; ps.p[7] = (const float*)d_in[12];
  ps.p[8] = (const float*)d_in[13];
  ps.p[9] = (const float*)d_in[3];  ps.p[10] = (const float*)d_in[4];
  prep<<<15104, 256, 0, stream>>>(F, FB, ps, WT, ADJ, ADJB, ADJT);

  const long long dA = (long long)(ADJT - ADJB);

  Seg Wmid = mkP(WT+10*SL,0,512, WT+9*SL,0,512, WMT,0,512, 512, 512,512, 2);
  Seg Tsg  = mkP(FB,sNC,512, WMT,0,512, TB,sNC,512, 512, 256,512, 2);
  Seg ScS; zero(ScS);
  ScS.A = TB; ScS.B = FB; ScS.O = Sb;
  ScS.sA = sNC; ScS.sB = sNC; ScS.sO = sNN;
  ScS.lda = 512; ScS.ldb = 512; ScS.ldc = 256;
  ScS.K = 512; ScS.flags = 64;

  Seg ST1  = mkF(FB,  WT+0*SL, SL, ADJB, dA, nullptr, Hb,  16|2);
  Seg ST2  = mkF(Hb,  WT+2*SL, SL, ADJB, dA, nullptr, Hb2, 16|2);
  Seg ST3  = mkF(Hb2, WT+4*SL, SL, ADJB, dA, nullptr, Hb,  16|2);
  Seg SIM1 = mkF(FB,  WT+6*SL, 0,  Sb,   0,  nullptr, Gb,  2);
  Seg SIM2 = mkF(Gb,  WT+7*SL, 0,  Sb,   0,  nullptr, Gb2, 2);
  Seg SIM3 = mkF(Gb2, WT+8*SL, 0,  Sb,   0,  Hb,      d_out, 4);   // fp32 out = relu(S@Y3) + Hst

  // ---- schedule: st chain || sim front-end (fused layers: 1024 blocks) ----
  L2(Wmid,16, ST1,1024);   // D2
  L2(Tsg,512, ST2,1024);   // D3
  L2(ScS,256, ST3,1024);   // D4
  L1(SIM1,1024);           // D5
  L1(SIM2,1024);           // D6
  L1(SIM3,1024);           // D7
}

// Round 6
// 348.513 us; speedup vs baseline: 1.3086x; 1.3086x over previous
//
#include <hip/hip_runtime.h>
#include <stdint.h>

#define DEVI __device__ __forceinline__

using bf16x8 = __attribute__((ext_vector_type(8))) __bf16;
using f32x4  = __attribute__((ext_vector_type(4))) float;

DEVI ushort f2bf(float f){
  uint32_t u = __float_as_uint(f);
  uint32_t r = u + 0x7fffu + ((u >> 16) & 1u);   // RNE
  return (ushort)(r >> 16);
}
DEVI float bf2f(ushort h){ return __uint_as_float(((uint32_t)h) << 16); }

// async 16B global -> LDS (wave-uniform LDS base; lane lands at base + lane*16)
DEVI void async16(const ushort* g, ushort* l, int lbyte) {
  __builtin_amdgcn_global_load_lds(
      (const __attribute__((address_space(1))) uint32_t*)g,
      (__attribute__((address_space(3))) uint32_t*)((char*)l + lbyte),
      16, 0, 0);
}

// ---------------------------------------------------------------------------
// Segmented mega kernel. Paths:
//  flags&128: FUSED GCN LAYER  out = relu(G @ (X @ Wslab)) [+ dual branch]
//             block = (z, 64-col slab), 512 blocks/layer.
//             DUAL-FUSED PHASE 1: Yf AND Yb computed in one sweep (X staged
//             once, both W tiles staged, 32 MFMA/step) -> steps 48->33,
//             staging -35%. Yb parked as packed bf16 in AGPRs (accvgpr asm;
//             allocator spilled it to scratch in R1/R4), dumped to Yt before
//             phase2-bwd. pk (fwd result) also AGPR-pinned.
//             Yt: 64x256 bf16, byte = col*512+row*2, XOR ((col&7)<<4) swizzle
//             (same key on dump and read) -> no pad, LDS = 81920 = 2 blk/CU.
//  flags&64 : fused Sc + row softmax (LDS-staged, pipelined)
//  else     : plain NT GEMM 128x128 tile, LDS-staged, double-buffered
// flags: 1=relu 2=out_bf16 4=add Src2 bf16 16=dual 64=ScS 128=fused layer
// ---------------------------------------------------------------------------
struct Seg {
  const ushort* A; const ushort* B; const void* Src; const void* Src2; void* O;
  long long sA, sB, sS, sS2, sO;
  int lda, ldb, ldS, ldS2, ldc;
  int K, nbx, nbxy, flags;
  long long A2off, B2off;
};

__global__ __launch_bounds__(256, 2)
void mega(Seg s0, Seg s1, Seg s2, int n0s, int n01)
{
  extern __shared__ __align__(16) ushort lds[];
  int bid = blockIdx.x;
  const Seg& s = (bid < n0s) ? s0 : ((bid < n01) ? s1 : s2);
  if (bid >= n0s) bid -= (bid < n01) ? n0s : n01;

  const int t = threadIdx.x;
  const int lane = t & 63, wave = t >> 6;
  const int lr = lane & 15, lq = lane >> 4;
  const int lb0 = __builtin_amdgcn_readfirstlane((t & 192) * 16);

#define MFMA16(Aa, Bb) { _Pragma("unroll") for (int x = 0; x < 4; x++)           \
    _Pragma("unroll") for (int y = 0; y < 4; y++)                                \
      acc[x][y] = __builtin_amdgcn_mfma_f32_16x16x32_bf16(Aa[x], Bb[y], acc[x][y], 0, 0, 0); }

  if (s.flags & 128) {
    // ================= fused GCN layer =================
    const int z    = (bid & 7) + ((bid >> 6) << 3);   // XCD swizzle: same z -> same XCD
    const int slab = (bid >> 3) & 7;
    const int n0   = slab * 64;

    // LDS map (bytes):
    //   [0, 32768)           Yt: 64 cols x 256 rows bf16, XOR ((col&7)<<4)
    //   [32768 + b*24576)    staging buf b: stA 16384 | stWf 4096 | stWb 4096
    const int r0 = t >> 2, c0 = (t & 3) * 8;

    const ushort* X  = s.A + (long long)z * s.sA;
    const ushort* Wf = s.B + (long long)n0 * 512;
    const ushort* G0 = (const ushort*)s.Src + (long long)z * s.sS;
    const ushort* pX  = X + (long long)r0 * 512 + c0;
    const ushort* pGf = G0 + (long long)r0 * s.ldS + c0;

    f32x4 acc[4][4] = {};

#define SOFF(b) (32768 + (b)*24576)

#define ISSUE1D(k0s, b) { const int _o = SOFF(b) + lb0;                          \
      _Pragma("unroll") for (int i = 0; i < 4; i++)                              \
        async16(pX + (long long)(64*i)*512 + (k0s), lds, _o + i*4096);           \
      async16(pWf + (k0s), lds, _o + 16384);                                     \
      async16(pWb + (k0s), lds, _o + 20480); }

#define ISSUE1S(k0s, b) { const int _o = SOFF(b) + lb0;                          \
      _Pragma("unroll") for (int i = 0; i < 4; i++)                              \
        async16(pX + (long long)(64*i)*512 + (k0s), lds, _o + i*4096);           \
      async16(pWf + (k0s), lds, _o + 16384); }

#define ISSUE2G(k0s, b, pG) { const int _o = SOFF(b) + lb0;                      \
      _Pragma("unroll") for (int i = 0; i < 4; i++)                              \
        async16((pG) + (long long)(64*i)*s.ldS + (k0s), lds, _o + i*4096); }

#define LDA4(curb, af) { const ushort* _sA = lds + 16384 + (curb)*12288;         \
      _Pragma("unroll") for (int x = 0; x < 4; x++)                              \
        af[x] = *(const bf16x8*)&_sA[(64*wave + x*16 + lr)*32 + lq*8]; }

#define COMP1D(curb) { bf16x8 af[4], bwf[4], bwb[4];                             \
      LDA4(curb, af);                                                            \
      const ushort* _sW = lds + 16384 + (curb)*12288 + 8192;                     \
      _Pragma("unroll") for (int y = 0; y < 4; y++) {                            \
        bwf[y] = *(const bf16x8*)&_sW[(y*16 + lr)*32 + lq*8];                    \
        bwb[y] = *(const bf16x8*)&_sW[2048 + (y*16 + lr)*32 + lq*8];             \
      }                                                                          \
      _Pragma("unroll") for (int x = 0; x < 4; x++)                              \
        _Pragma("unroll") for (int y = 0; y < 4; y++) {                          \
          acc[x][y]  = __builtin_amdgcn_mfma_f32_16x16x32_bf16(af[x], bwf[y], acc[x][y], 0, 0, 0);  \
          accB[x][y] = __builtin_amdgcn_mfma_f32_16x16x32_bf16(af[x], bwb[y], accB[x][y], 0, 0, 0); \
        } }

#define COMP1S(curb) { bf16x8 af[4], bwf[4];                                     \
      LDA4(curb, af);                                                            \
      const ushort* _sW = lds + 16384 + (curb)*12288 + 8192;                     \
      _Pragma("unroll") for (int y = 0; y < 4; y++)                              \
        bwf[y] = *(const bf16x8*)&_sW[(y*16 + lr)*32 + lq*8];                    \
      MFMA16(af, bwf); }

#define COMP2(curb, kk) { bf16x8 af[4], bfr[4];                                  \
      LDA4(curb, af);                                                            \
      _Pragma("unroll") for (int y = 0; y < 4; y++) {                            \
        const int _c = y*16 + lr;                                                \
        bfr[y] = *(const bf16x8*)((const char*)lds +                             \
                   ((_c*512 + (kk)*2 + lq*16) ^ ((_c & 7) << 4)));               \
      }                                                                          \
      MFMA16(af, bfr); }

#define DUMPA() { _Pragma("unroll") for (int x = 0; x < 4; x++)                  \
      _Pragma("unroll") for (int y = 0; y < 4; y++) {                            \
        const int _c = y*16 + lr;                                                \
        const int _rb = 64*wave + x*16 + lq*4;                                   \
        uint2 vv;                                                                \
        vv.x = (uint)f2bf(acc[x][y][0]) | ((uint)f2bf(acc[x][y][1]) << 16);      \
        vv.y = (uint)f2bf(acc[x][y][2]) | ((uint)f2bf(acc[x][y][3]) << 16);      \
        *(uint2*)((char*)lds + ((_c*512 + _rb*2) ^ ((_c & 7) << 4))) = vv;       \
        acc[x][y] = (f32x4){0.f, 0.f, 0.f, 0.f};                                 \
      } }

    if (s.flags & 16) {
      // ---------------- dual branch ----------------
      const ushort* pWf = Wf + (long long)r0 * 512 + c0;
      const ushort* pWb = Wf + s.B2off + (long long)r0 * 512 + c0;
      const ushort* pGb = G0 + s.A2off + (long long)r0 * s.ldS + c0;
      f32x4 accB[4][4] = {};
      uint pk[4][4][2], pkb[4][4][2];

      // ---- phase 1 (fused): {Yf, Yb} = X @ {Wf, Wb}, K=512 ----
      ISSUE1D(0, 0);
      for (int k0 = 0; k0 < 480; k0 += 32) {
        const int cur = (k0 >> 5) & 1;
        __syncthreads();               // buf cur ready
        ISSUE1D(k0 + 32, cur ^ 1);     // flies under the 32 MFMAs below
        COMP1D(cur);
      }
      __syncthreads();                 // buf1 ready; buf0 reads done
      ISSUE2G(0, 0, pGf);              // prefetch fwd-G step0 into buf0
      COMP1D(1);
      // park Yb as packed bf16 in AGPRs; dump Yf -> Yt
      #pragma unroll
      for (int x = 0; x < 4; x++)
        #pragma unroll
        for (int y = 0; y < 4; y++) {
          uint b0 = (uint)f2bf(accB[x][y][0]) | ((uint)f2bf(accB[x][y][1]) << 16);
          uint b1 = (uint)f2bf(accB[x][y][2]) | ((uint)f2bf(accB[x][y][3]) << 16);
          asm("v_accvgpr_write_b32 %0, %1" : "=a"(pkb[x][y][0]) : "v"(b0));
          asm("v_accvgpr_write_b32 %0, %1" : "=a"(pkb[x][y][1]) : "v"(b1));
        }
      DUMPA();
      // ---- phase 2 fwd: acc = Gf @ Yf ----
      for (int k0 = 0; k0 < 224; k0 += 32) {
        const int cur = (k0 >> 5) & 1;
        __syncthreads();               // iter0: Yt visible + buf0 landed
        ISSUE2G(k0 + 32, cur ^ 1, pGf);
        COMP2(cur, k0);
      }
      __syncthreads();                 // buf1 ready; buf0 free
      ISSUE2G(0, 0, pGb);              // prefetch bwd-G step0
      COMP2(1, 224);
      // pk <- relu(fwd result), AGPR-pinned; reset acc
      #pragma unroll
      for (int x = 0; x < 4; x++)
        #pragma unroll
        for (int y = 0; y < 4; y++) {
          uint p0 = (uint)f2bf(fmaxf(acc[x][y][0],0.f)) | ((uint)f2bf(fmaxf(acc[x][y][1],0.f)) << 16);
          uint p1 = (uint)f2bf(fmaxf(acc[x][y][2],0.f)) | ((uint)f2bf(fmaxf(acc[x][y][3],0.f)) << 16);
          asm("v_accvgpr_write_b32 %0, %1" : "=a"(pk[x][y][0]) : "v"(p0));
          asm("v_accvgpr_write_b32 %0, %1" : "=a"(pk[x][y][1]) : "v"(p1));
          acc[x][y] = (f32x4){0.f, 0.f, 0.f, 0.f};
        }
      __syncthreads();                 // all waves done reading Yt (fwd)
      // dump Yb (from AGPR-packed pkb) -> Yt
      #pragma unroll
      for (int x = 0; x < 4; x++)
        #pragma unroll
        for (int y = 0; y < 4; y++) {
          const int _c = y*16 + lr;
          const int _rb = 64*wave + x*16 + lq*4;
          uint a0, a1;
          asm("v_accvgpr_read_b32 %0, %1" : "=v"(a0) : "a"(pkb[x][y][0]));
          asm("v_accvgpr_read_b32 %0, %1" : "=v"(a1) : "a"(pkb[x][y][1]));
          uint2 vv; vv.x = a0; vv.y = a1;
          *(uint2*)((char*)lds + ((_c*512 + _rb*2) ^ ((_c & 7) << 4))) = vv;
        }
      // ---- phase 2 bwd: acc = Gb @ Yb ----
      for (int k0 = 0; k0 < 224; k0 += 32) {
        const int cur = (k0 >> 5) & 1;
        __syncthreads();               // iter0: Yt_b visible + buf0 landed
        ISSUE2G(k0 + 32, cur ^ 1, pGb);
        COMP2(cur, k0);
      }
      __syncthreads();
      COMP2(1, 224);
      // ---- epilogue: relu(bwd) + pk(fwd) ----
      {
        const int fl = s.flags;
        #pragma unroll
        for (int x = 0; x < 4; x++)
          #pragma unroll
          for (int y = 0; y < 4; y++) {
            const int col = n0 + y*16 + lr;
            uint w0, w1;
            asm("v_accvgpr_read_b32 %0, %1" : "=v"(w0) : "a"(pk[x][y][0]));
            asm("v_accvgpr_read_b32 %0, %1" : "=v"(w1) : "a"(pk[x][y][1]));
            #pragma unroll
            for (int r = 0; r < 4; r++) {
              const int row = 64*wave + x*16 + lq*4 + r;
              float v = fmaxf(acc[x][y][r], 0.f);
              v += bf2f((ushort)(((r >> 1) ? w1 : w0) >> (16*(r & 1))));
              if (fl & 4)  v += bf2f(((const ushort*)s.Src2)[(long long)z*s.sS2 + (long long)row*s.ldS2 + col]);
              if (fl & 2)
                ((ushort*)s.O)[(long long)z*s.sO + (long long)row*s.ldc + col] = f2bf(v);
              else
                ((float*)s.O)[(long long)z*s.sO + (long long)row*s.ldc + col] = v;
            }
          }
      }
    } else {
      // ---------------- single branch ----------------
      const ushort* pWf = Wf + (long long)r0 * 512 + c0;
      ISSUE1S(0, 0);
      for (int k0 = 0; k0 < 480; k0 += 32) {
        const int cur = (k0 >> 5) & 1;
        __syncthreads();
        ISSUE1S(k0 + 32, cur ^ 1);
        COMP1S(cur);
      }
      __syncthreads();
      ISSUE2G(0, 0, pGf);
      COMP1S(1);
      DUMPA();
      for (int k0 = 0; k0 < 224; k0 += 32) {
        const int cur = (k0 >> 5) & 1;
        __syncthreads();
        ISSUE2G(k0 + 32, cur ^ 1, pGf);
        COMP2(cur, k0);
      }
      __syncthreads();
      COMP2(1, 224);
      {
        const int fl = s.flags;
        #pragma unroll
        for (int x = 0; x < 4; x++)
          #pragma unroll
          for (int y = 0; y < 4; y++) {
            const int col = n0 + y*16 + lr;
            #pragma unroll
            for (int r = 0; r < 4; r++) {
              const int row = 64*wave + x*16 + lq*4 + r;
              float v = fmaxf(acc[x][y][r], 0.f);
              if (fl & 4)  v += bf2f(((const ushort*)s.Src2)[(long long)z*s.sS2 + (long long)row*s.ldS2 + col]);
              if (fl & 2)
                ((ushort*)s.O)[(long long)z*s.sO + (long long)row*s.ldc + col] = f2bf(v);
              else
                ((float*)s.O)[(long long)z*s.sO + (long long)row*s.ldc + col] = v;
            }
          }
      }
    }
    return;
  }

  if (s.flags & 64) {
    // ================= fused Sc + row softmax =================
    const int niter = s.K >> 5;
    const int z = bid >> 2, mb = bid & 3;
    const ushort* pa = s.A + (long long)z*s.sA + (long long)(mb*64 + (t >> 2))*s.lda + (t & 3)*8;
    const ushort* pb = s.B + (long long)z*s.sB + (long long)(t >> 2)*s.ldb + (t & 3)*8;
    const long long b64 = 64ll*s.ldb;

    f32x4 acc[16] = {};
#define ISSUE_S(idx) { const int _i=(idx); const int _o=(_i&1)*20480 + lb0;      \
    const int _k=_i<<5;                                                          \
    async16(pa + _k, lds, _o);                                                   \
    async16(pb + _k,        lds, _o + 4096);                                     \
    async16(pb + b64 + _k,  lds, _o + 8192);                                     \
    async16(pb + 2*b64 + _k,lds, _o + 12288);                                    \
    async16(pb + 3*b64 + _k,lds, _o + 16384); }
    ISSUE_S(0);
    for (int i = 0; i < niter; ++i) {
      __syncthreads();
      if (i + 1 < niter) ISSUE_S(i + 1);
      const ushort* LA = lds + (i & 1)*10240;
      const ushort* LB = LA + 2048;
      const bf16x8 af = *(const bf16x8*)&LA[(wave*16 + lr)*32 + lq*8];
      #pragma unroll
      for (int j = 0; j < 16; j++) {
        const bf16x8 bfr = *(const bf16x8*)&LB[(j*16 + lr)*32 + lq*8];
        acc[j] = __builtin_amdgcn_mfma_f32_16x16x32_bf16(af, bfr, acc[j], 0, 0, 0);
      }
    }
    float mx[4] = {-1e30f, -1e30f, -1e30f, -1e30f};
    #pragma unroll
    for (int j = 0; j < 16; j++)
      #pragma unroll
      for (int r = 0; r < 4; r++) mx[r] = fmaxf(mx[r], acc[j][r]);
    #pragma unroll
    for (int r = 0; r < 4; r++)
      #pragma unroll
      for (int off = 1; off <= 8; off <<= 1) mx[r] = fmaxf(mx[r], __shfl_xor(mx[r], off, 64));
    float sm[4] = {0.f, 0.f, 0.f, 0.f};
    #pragma unroll
    for (int j = 0; j < 16; j++)
      #pragma unroll
      for (int r = 0; r < 4; r++) { float e = __expf(acc[j][r] - mx[r]); acc[j][r] = e; sm[r] += e; }
    #pragma unroll
    for (int r = 0; r < 4; r++) {
      #pragma unroll
      for (int off = 1; off <= 8; off <<= 1) sm[r] += __shfl_xor(sm[r], off, 64);
      sm[r] = 1.0f / sm[r];
    }
    ushort* Oz = (ushort*)s.O + (long long)z*s.sO;
    #pragma unroll
    for (int j = 0; j < 16; j++)
      #pragma unroll
      for (int r = 0; r < 4; r++) {
        const int row = mb*64 + wave*16 + lq*4 + r;
        Oz[(long long)row*s.ldc + j*16 + lr] = f2bf(acc[j][r]*sm[r]);
      }
    return;
  }

  // ================= plain NT GEMM, double-buffered =================
  {
    // buf b (bytes): lA 128x32 at b*16384, lB 128x32 at b*16384 + 8192
    const int z  = bid / s.nbxy;
    const int rz = bid % s.nbxy;
    const int bx = rz % s.nbx, by = rz / s.nbx;
    const int wm = (wave >> 1)*64, wn = (wave & 1)*64;
    const int r0 = t >> 2, c0 = (t & 3)*8;

    const ushort* pa = s.A + (long long)z*s.sA + (long long)(by*128 + r0)*s.lda + c0;
    const ushort* pb = s.B + (long long)z*s.sB + (long long)(bx*128 + r0)*s.ldb + c0;
    const long long a64 = 64ll*s.lda, b64 = 64ll*s.ldb;

#define ISSUEP(k0s, b) { const int _o = (b)*16384 + lb0;                         \
      async16(pa + (k0s),       lds, _o);                                        \
      async16(pa + a64 + (k0s), lds, _o + 4096);                                 \
      async16(pb + (k0s),       lds, _o + 8192);                                 \
      async16(pb + b64 + (k0s), lds, _o + 12288); }

#define COMPUTEP(curb) {                                                         \
      const ushort* lA = (const ushort*)((const char*)lds + (curb)*16384);       \
      const ushort* lB = lA + 4096;                                              \
      bf16x8 af[4], bfr[4];                                                      \
      _Pragma("unroll") for (int x = 0; x < 4; x++) {                            \
        af[x]  = *(const bf16x8*)&lA[(wm + x*16 + lr)*32 + lq*8];                \
        bfr[x] = *(const bf16x8*)&lB[(wn + x*16 + lr)*32 + lq*8];                \
      }                                                                          \
      MFMA16(af, bfr); }

    f32x4 acc[4][4] = {};
    ISSUEP(0, 0);
    int k0 = 0;
    for (; k0 < s.K - 32; k0 += 32) {
      const int cur = (k0 >> 5) & 1;
      __syncthreads();                 // buf cur ready
      ISSUEP(k0 + 32, cur ^ 1);
      COMPUTEP(cur);
    }
    __syncthreads();
    COMPUTEP((k0 >> 5) & 1);
    const int rowb = by*128 + wm + lq*4;
    const int colb = bx*128 + wn + lr;
    const int fl = s.flags;
    #pragma unroll
    for (int x = 0; x < 4; x++)
      #pragma unroll
      for (int y = 0; y < 4; y++) {
        const int col = colb + y*16;
        #pragma unroll
        for (int r = 0; r < 4; r++) {
          const int row = rowb + x*16 + r;
          float v = acc[x][y][r];
          if (fl & 1) v = fmaxf(v, 0.f);
          if (fl & 2)
            ((ushort*)s.O)[(long long)z*s.sO + (long long)row*s.ldc + col] = f2bf(v);
          else
            ((float*)s.O)[(long long)z*s.sO + (long long)row*s.ldc + col] = v;
        }
      }
  }
}

// ---------------------------------------------------------------------------
// fused prep: [0,8192) cast f -> bf16 ; [8192,11008) 11 weight transposes ;
// [11008,15104) adj -> adj/adjT bf16
// ---------------------------------------------------------------------------
struct P11 { const float* p[11]; };

__global__ void prep(const float* __restrict__ F, ushort* __restrict__ FB,
                     P11 ps, ushort* __restrict__ WT,
                     const float* __restrict__ ADJ, ushort* __restrict__ AB,
                     ushort* __restrict__ ATB)
{
  __shared__ float tile[32][33];
  const int b = blockIdx.x, t = threadIdx.x;
  if (b < 8192) {
    const int i = b*256 + t;
    const float4 v = ((const float4*)F)[i];
    ushort4 o; o.x = f2bf(v.x); o.y = f2bf(v.y); o.z = f2bf(v.z); o.w = f2bf(v.w);
    ((ushort4*)FB)[i] = o;
  } else if (b < 11008) {
    const int q = b - 8192;
    const int wdx = q >> 8, tl = q & 255;
    const int bo = (tl & 15)*32, bk = (tl >> 4)*32;
    const int tx = t & 31, ty = t >> 5;
    const float* in = ps.p[wdx];
    ushort* o = WT + (long long)wdx*262144;
    #pragma unroll
    for (int r = 0; r < 32; r += 8) tile[ty+r][tx] = in[(long long)(bk+ty+r)*512 + bo+tx];
    __syncthreads();
    #pragma unroll
    for (int r = 0; r < 32; r += 8) o[(long long)(bo+ty+r)*512 + bk+tx] = f2bf(tile[tx][ty+r]);
  } else {
    const int q = b - 11008;
    const long long base = (long long)(q >> 6)*65536;
    const int bi = ((q >> 3) & 7)*32, bj = (q & 7)*32;
    const int tx = t & 31, ty = t >> 5;
    #pragma unroll
    for (int r = 0; r < 32; r += 8) {
      const float v = ADJ[base + (long long)(bi+ty+r)*256 + bj+tx];
      tile[ty+r][tx] = v;
      AB[base + (long long)(bi+ty+r)*256 + bj+tx] = f2bf(v);
    }
    __syncthreads();
    #pragma unroll
    for (int r = 0; r < 32; r += 8)
      ATB[base + (long long)(bj+ty+r)*256 + bi+tx] = f2bf(tile[tx][ty+r]);
  }
}

// ---------------------------------------------------------------------------
extern "C" void kernel_launch(void* const* d_in, const int* in_sizes, int n_in,
                              void* d_out, int out_size, void* d_ws, size_t ws_size,
                              hipStream_t stream)
{
  (void)in_sizes; (void)n_in; (void)out_size;
  const float* F   = (const float*)d_in[0];
  const float* ADJ = (const float*)d_in[2];

  uint8_t* w = (uint8_t*)d_ws;
  size_t off = 0;
  auto alloc = [&](size_t bytes) -> void* { void* p = w + off; off += (bytes + 255) & ~(size_t)255; return p; };

  const long long SL = 262144;
  ushort* WT   = (ushort*)alloc(11*524288);  // 0:Wst1 1:Wst1b 2:Wst2 3:Wst2b 4:Wst3 5:Wst3b 6-8:Wsim1-3 9:Wse1T 10:Wse2T
  ushort* WMT  = (ushort*)alloc(524288);
  ushort* FB   = (ushort*)alloc(16777216);
  ushort* ADJB = (ushort*)alloc(8388608);
  ushort* ADJT = (ushort*)alloc(8388608);
  ushort* TB   = (ushort*)alloc(16777216);
  ushort* Sb   = (ushort*)alloc(8388608);
  ushort* Hb   = (ushort*)alloc(16777216);   // st ping
  ushort* Hb2  = (ushort*)alloc(16777216);   // st pong
  ushort* Gb   = (ushort*)alloc(16777216);   // sim ping
  ushort* Gb2  = (ushort*)alloc(16777216);   // sim pong
  if (off > ws_size) return;

  const long long sNC = 131072, sNN = 65536;
  const int LDSB = 81920;   // Yt 32768 + 2x24576 staging dbuf = exactly 2 blocks/CU

  auto zero = [](Seg& s) {
    s.A = nullptr; s.B = nullptr; s.Src = nullptr; s.Src2 = nullptr; s.O = nullptr;
    s.sA = s.sB = s.sS = s.sS2 = s.sO = 0;
    s.lda = s.ldb = s.ldS = s.ldS2 = s.ldc = 0;
    s.K = 0; s.nbx = 1; s.nbxy = 1; s.flags = 0; s.A2off = s.B2off = 0;
  };
  auto mkP = [&](const void* A, long long sA, int lda, const void* B, long long sB, int ldb,
                 void* O, long long sO, int ldc, int K, int M, int Nn, int flags) -> Seg {
    Seg s; zero(s);
    s.A = (const ushort*)A; s.B = (const ushort*)B; s.O = O;
    s.sA = sA; s.sB = sB; s.sO = sO;
    s.lda = lda; s.ldb = ldb; s.ldc = ldc;
    s.K = K; s.nbx = Nn/128; s.nbxy = (Nn/128)*(M/128); s.flags = flags;
    return s;
  };
  auto mkF = [&](const void* X, const void* Wf, long long B2off, const void* G, long long A2off,
                 const void* Src2, void* O, int flags) -> Seg {
    Seg s; zero(s);
    s.A = (const ushort*)X; s.sA = sNC; s.lda = 512;
    s.B = (const ushort*)Wf; s.B2off = B2off;
    s.Src = G; s.sS = sNN; s.ldS = 256; s.A2off = A2off;
    s.Src2 = Src2; s.sS2 = sNC; s.ldS2 = 512;
    s.O = O; s.sO = sNC; s.ldc = 512;
    s.flags = 128 | flags;
    return s;
  };
  auto L1 = [&](const Seg& a, int na) { mega<<<na, 256, LDSB, stream>>>(a, a, a, na, na); };
  auto L2 = [&](const Seg& a, int na, const Seg& b, int nb) {
    mega<<<na+nb, 256, LDSB, stream>>>(a, b, b, na, na+nb); };

  // ---- D1: fused prep ----
  P11 ps;
  ps.p[0] = (const float*)d_in[5];  ps.p[1] = (const float*)d_in[8];
  ps.p[2] = (const float*)d_in[6];  ps.p[3] = (const float*)d_in[9];
  ps.p[4] = (const float*)d_in[7];  ps.p[5] = (const float*)d_in[10];
  ps.p[6] = (const float*)d_in[11]; ps.p[7] = (const float*)d_in[12];
  ps.p[8] = (const float*)d_in[13];
  ps.p[9] = (const float*)d_in[3];  ps.p[10] = (const float*)d_in[4];
  prep<<<15104, 256, 0, stream>>>(F, FB, ps, WT, ADJ, ADJB, ADJT);

  const long long dA = (long long)(ADJT - ADJB);

  Seg Wmid = mkP(WT+10*SL,0,512, WT+9*SL,0,512, WMT,0,512, 512, 512,512, 2);
  Seg Tsg  = mkP(FB,sNC,512, WMT,0,512, TB,sNC,512, 512, 256,512, 2);
  Seg ScS; zero(ScS);
  ScS.A = TB; ScS.B = FB; ScS.O = Sb;
  ScS.sA = sNC; ScS.sB = sNC; ScS.sO = sNN;
  ScS.lda = 512; ScS.ldb = 512; ScS.ldc = 256;
  ScS.K = 512; ScS.flags = 64;

  Seg ST1  = mkF(FB,  WT+0*SL, SL, ADJB, dA, nullptr, Hb,  16|2);
  Seg ST2  = mkF(Hb,  WT+2*SL, SL, ADJB, dA, nullptr, Hb2, 16|2);
  Seg ST3  = mkF(Hb2, WT+4*SL, SL, ADJB, dA, nullptr, Hb,  16|2);
  Seg SIM1 = mkF(FB,  WT+6*SL, 0,  Sb,   0,  nullptr, Gb,  2);
  Seg SIM2 = mkF(Gb,  WT+7*SL, 0,  Sb,   0,  nullptr, Gb2, 2);
  Seg SIM3 = mkF(Gb2, WT+8*SL, 0,  Sb,   0,  Hb,      d_out, 4);   // fp32 out = relu(S@Y3) + Hst

  // ---- schedule: st chain || sim front-end ----
  L2(Wmid,16, ST1,512);   // D2
  L2(Tsg,512, ST2,512);   // D3
  L2(ScS,256, ST3,512);   // D4
  L1(SIM1,512);           // D5
  L1(SIM2,512);           // D6
  L1(SIM3,512);           // D7
}

// Round 10
// 347.917 us; speedup vs baseline: 1.3109x; 1.0017x over previous
//
#include <hip/hip_runtime.h>
#include <stdint.h>

#define DEVI __device__ __forceinline__

using bf16x8 = __attribute__((ext_vector_type(8))) __bf16;
using f32x4  = __attribute__((ext_vector_type(4))) float;

DEVI ushort f2bf(float f){
  uint32_t u = __float_as_uint(f);
  uint32_t r = u + 0x7fffu + ((u >> 16) & 1u);   // RNE
  return (ushort)(r >> 16);
}
DEVI float bf2f(ushort h){ return __uint_as_float(((uint32_t)h) << 16); }

// async 16B global -> LDS (wave-uniform LDS base; lane lands at base + lane*16)
DEVI void async16(const ushort* g, ushort* l, int lbyte) {
  __builtin_amdgcn_global_load_lds(
      (const __attribute__((address_space(1))) uint32_t*)g,
      (__attribute__((address_space(3))) uint32_t*)((char*)l + lbyte),
      16, 0, 0);
}

// ---------------------------------------------------------------------------
// Segmented mega kernel (R6-proven structure; R7/R8's counted-vmcnt 3-buffer
// pipeline produced deterministic corruption — hypothesis: counted
// s_waitcnt vmcnt(N) is contaminated by compiler-generated vmem (spill
// reloads / hoisted loads), under-waiting the staging tile. Without disasm
// verification the counted pipeline is unsafe at HIP level; __syncthreads's
// vmcnt(0) drain is immune.)
// Paths:
//  flags&128: FUSED GCN LAYER  out = relu(G @ (X @ Wslab)) [+ dual branch]
//             block = (z, 64-col slab), 512 blocks/layer.
//             DUAL-FUSED PHASE 1: Yf AND Yb computed in one sweep (X staged
//             once, both W tiles staged, 32 MFMA/step). Yb parked as packed
//             bf16 in AGPRs (accvgpr asm), dumped to Yt before phase2-bwd.
//             pk (fwd result) also AGPR-pinned.
//             Yt: 64x256 bf16, byte = col*512+row*2, XOR ((col&7)<<4) swizzle
//             (same key on dump and read) -> no pad, LDS = 81920 = 2 blk/CU.
//  flags&64 : fused Sc + row softmax (LDS-staged, pipelined)
//  else     : plain NT GEMM 128x128 tile, LDS-staged, double-buffered
// flags: 1=relu 2=out_bf16 4=add Src2 bf16 16=dual 64=ScS 128=fused layer
// ---------------------------------------------------------------------------
struct Seg {
  const ushort* A; const ushort* B; const void* Src; const void* Src2; void* O;
  long long sA, sB, sS, sS2, sO;
  int lda, ldb, ldS, ldS2, ldc;
  int K, nbx, nbxy, flags;
  long long A2off, B2off;
};

__global__ __launch_bounds__(256, 2)
void mega(Seg s0, Seg s1, Seg s2, int n0s, int n01)
{
  extern __shared__ __align__(16) ushort lds[];
  int bid = blockIdx.x;
  const Seg& s = (bid < n0s) ? s0 : ((bid < n01) ? s1 : s2);
  if (bid >= n0s) bid -= (bid < n01) ? n0s : n01;

  const int t = threadIdx.x;
  const int lane = t & 63, wave = t >> 6;
  const int lr = lane & 15, lq = lane >> 4;
  const int lb0 = __builtin_amdgcn_readfirstlane((t & 192) * 16);

#define MFMA16(Aa, Bb) { _Pragma("unroll") for (int x = 0; x < 4; x++)           \
    _Pragma("unroll") for (int y = 0; y < 4; y++)                                \
      acc[x][y] = __builtin_amdgcn_mfma_f32_16x16x32_bf16(Aa[x], Bb[y], acc[x][y], 0, 0, 0); }

  if (s.flags & 128) {
    // ================= fused GCN layer =================
    const int z    = (bid & 7) + ((bid >> 6) << 3);   // XCD swizzle: same z -> same XCD
    const int slab = (bid >> 3) & 7;
    const int n0   = slab * 64;

    // LDS map (bytes):
    //   [0, 32768)           Yt: 64 cols x 256 rows bf16, XOR ((col&7)<<4)
    //   [32768 + b*24576)    staging buf b: stA 16384 | stWf 4096 | stWb 4096
    const int r0 = t >> 2, c0 = (t & 3) * 8;

    const ushort* X  = s.A + (long long)z * s.sA;
    const ushort* Wf = s.B + (long long)n0 * 512;
    const ushort* G0 = (const ushort*)s.Src + (long long)z * s.sS;
    const ushort* pX  = X + (long long)r0 * 512 + c0;
    const ushort* pGf = G0 + (long long)r0 * s.ldS + c0;

    f32x4 acc[4][4] = {};

#define SOFF(b) (32768 + (b)*24576)

#define ISSUE1D(k0s, b) { const int _o = SOFF(b) + lb0;                          \
      _Pragma("unroll") for (int i = 0; i < 4; i++)                              \
        async16(pX + (long long)(64*i)*512 + (k0s), lds, _o + i*4096);           \
      async16(pWf + (k0s), lds, _o + 16384);                                     \
      async16(pWb + (k0s), lds, _o + 20480); }

#define ISSUE1S(k0s, b) { const int _o = SOFF(b) + lb0;                          \
      _Pragma("unroll") for (int i = 0; i < 4; i++)                              \
        async16(pX + (long long)(64*i)*512 + (k0s), lds, _o + i*4096);           \
      async16(pWf + (k0s), lds, _o + 16384); }

#define ISSUE2G(k0s, b, pG) { const int _o = SOFF(b) + lb0;                      \
      _Pragma("unroll") for (int i = 0; i < 4; i++)                              \
        async16((pG) + (long long)(64*i)*s.ldS + (k0s), lds, _o + i*4096); }

#define LDA4(curb, af) { const ushort* _sA = lds + 16384 + (curb)*12288;         \
      _Pragma("unroll") for (int x = 0; x < 4; x++)                              \
        af[x] = *(const bf16x8*)&_sA[(64*wave + x*16 + lr)*32 + lq*8]; }

#define COMP1D(curb) { bf16x8 af[4], bwf[4], bwb[4];                             \
      LDA4(curb, af);                                                            \
      const ushort* _sW = lds + 16384 + (curb)*12288 + 8192;                     \
      _Pragma("unroll") for (int y = 0; y < 4; y++) {                            \
        bwf[y] = *(const bf16x8*)&_sW[(y*16 + lr)*32 + lq*8];                    \
        bwb[y] = *(const bf16x8*)&_sW[2048 + (y*16 + lr)*32 + lq*8];             \
      }                                                                          \
      _Pragma("unroll") for (int x = 0; x < 4; x++)                              \
        _Pragma("unroll") for (int y = 0; y < 4; y++) {                          \
          acc[x][y]  = __builtin_amdgcn_mfma_f32_16x16x32_bf16(af[x], bwf[y], acc[x][y], 0, 0, 0);  \
          accB[x][y] = __builtin_amdgcn_mfma_f32_16x16x32_bf16(af[x], bwb[y], accB[x][y], 0, 0, 0); \
        } }

#define COMP1S(curb) { bf16x8 af[4], bwf[4];                                     \
      LDA4(curb, af);                                                            \
      const ushort* _sW = lds + 16384 + (curb)*12288 + 8192;                     \
      _Pragma("unroll") for (int y = 0; y < 4; y++)                              \
        bwf[y] = *(const bf16x8*)&_sW[(y*16 + lr)*32 + lq*8];                    \
      MFMA16(af, bwf); }

#define COMP2(curb, kk) { bf16x8 af[4], bfr[4];                                  \
      LDA4(curb, af);                                                            \
      _Pragma("unroll") for (int y = 0; y < 4; y++) {                            \
        const int _c = y*16 + lr;                                                \
        bfr[y] = *(const bf16x8*)((const char*)lds +                             \
                   ((_c*512 + (kk)*2 + lq*16) ^ ((_c & 7) << 4)));               \
      }                                                                          \
      MFMA16(af, bfr); }

#define DUMPA() { _Pragma("unroll") for (int x = 0; x < 4; x++)                  \
      _Pragma("unroll") for (int y = 0; y < 4; y++) {                            \
        const int _c = y*16 + lr;                                                \
        const int _rb = 64*wave + x*16 + lq*4;                                   \
        uint2 vv;                                                                \
        vv.x = (uint)f2bf(acc[x][y][0]) | ((uint)f2bf(acc[x][y][1]) << 16);      \
        vv.y = (uint)f2bf(acc[x][y][2]) | ((uint)f2bf(acc[x][y][3]) << 16);      \
        *(uint2*)((char*)lds + ((_c*512 + _rb*2) ^ ((_c & 7) << 4))) = vv;       \
        acc[x][y] = (f32x4){0.f, 0.f, 0.f, 0.f};                                 \
      } }

    if (s.flags & 16) {
      // ---------------- dual branch ----------------
      const ushort* pWf = Wf + (long long)r0 * 512 + c0;
      const ushort* pWb = Wf + s.B2off + (long long)r0 * 512 + c0;
      const ushort* pGb = G0 + s.A2off + (long long)r0 * s.ldS + c0;
      f32x4 accB[4][4] = {};
      uint pk[4][4][2], pkb[4][4][2];

      // ---- phase 1 (fused): {Yf, Yb} = X @ {Wf, Wb}, K=512 ----
      ISSUE1D(0, 0);
      for (int k0 = 0; k0 < 480; k0 += 32) {
        const int cur = (k0 >> 5) & 1;
        __syncthreads();               // buf cur ready
        ISSUE1D(k0 + 32, cur ^ 1);     // flies under the 32 MFMAs below
        COMP1D(cur);
      }
      __syncthreads();                 // buf1 ready; buf0 reads done
      ISSUE2G(0, 0, pGf);              // prefetch fwd-G step0 into buf0
      COMP1D(1);
      // park Yb as packed bf16 in AGPRs; dump Yf -> Yt
      #pragma unroll
      for (int x = 0; x < 4; x++)
        #pragma unroll
        for (int y = 0; y < 4; y++) {
          uint b0 = (uint)f2bf(accB[x][y][0]) | ((uint)f2bf(accB[x][y][1]) << 16);
          uint b1 = (uint)f2bf(accB[x][y][2]) | ((uint)f2bf(accB[x][y][3]) << 16);
          asm("v_accvgpr_write_b32 %0, %1" : "=a"(pkb[x][y][0]) : "v"(b0));
          asm("v_accvgpr_write_b32 %0, %1" : "=a"(pkb[x][y][1]) : "v"(b1));
        }
      DUMPA();
      // ---- phase 2 fwd: acc = Gf @ Yf ----
      for (int k0 = 0; k0 < 224; k0 += 32) {
        const int cur = (k0 >> 5) & 1;
        __syncthreads();               // iter0: Yt visible + buf0 landed
        ISSUE2G(k0 + 32, cur ^ 1, pGf);
        COMP2(cur, k0);
      }
      __syncthreads();                 // buf1 ready; buf0 free
      ISSUE2G(0, 0, pGb);              // prefetch bwd-G step0
      COMP2(1, 224);
      // pk <- relu(fwd result), AGPR-pinned; reset acc
      #pragma unroll
      for (int x = 0; x < 4; x++)
        #pragma unroll
        for (int y = 0; y < 4; y++) {
          uint p0 = (uint)f2bf(fmaxf(acc[x][y][0],0.f)) | ((uint)f2bf(fmaxf(acc[x][y][1],0.f)) << 16);
          uint p1 = (uint)f2bf(fmaxf(acc[x][y][2],0.f)) | ((uint)f2bf(fmaxf(acc[x][y][3],0.f)) << 16);
          asm("v_accvgpr_write_b32 %0, %1" : "=a"(pk[x][y][0]) : "v"(p0));
          asm("v_accvgpr_write_b32 %0, %1" : "=a"(pk[x][y][1]) : "v"(p1));
          acc[x][y] = (f32x4){0.f, 0.f, 0.f, 0.f};
        }
      __syncthreads();                 // all waves done reading Yt (fwd)
      // dump Yb (from AGPR-packed pkb) -> Yt
      #pragma unroll
      for (int x = 0; x < 4; x++)
        #pragma unroll
        for (int y = 0; y < 4; y++) {
          const int _c = y*16 + lr;
          const int _rb = 64*wave + x*16 + lq*4;
          uint a0, a1;
          asm("v_accvgpr_read_b32 %0, %1" : "=v"(a0) : "a"(pkb[x][y][0]));
          asm("v_accvgpr_read_b32 %0, %1" : "=v"(a1) : "a"(pkb[x][y][1]));
          uint2 vv; vv.x = a0; vv.y = a1;
          *(uint2*)((char*)lds + ((_c*512 + _rb*2) ^ ((_c & 7) << 4))) = vv;
        }
      // ---- phase 2 bwd: acc = Gb @ Yb ----
      for (int k0 = 0; k0 < 224; k0 += 32) {
        const int cur = (k0 >> 5) & 1;
        __syncthreads();               // iter0: Yt_b visible + buf0 landed
        ISSUE2G(k0 + 32, cur ^ 1, pGb);
        COMP2(cur, k0);
      }
      __syncthreads();
      COMP2(1, 224);
      // ---- epilogue: relu(bwd) + pk(fwd) ----
      {
        const int fl = s.flags;
        #pragma unroll
        for (int x = 0; x < 4; x++)
          #pragma unroll
          for (int y = 0; y < 4; y++) {
            const int col = n0 + y*16 + lr;
            uint w0, w1;
            asm("v_accvgpr_read_b32 %0, %1" : "=v"(w0) : "a"(pk[x][y][0]));
            asm("v_accvgpr_read_b32 %0, %1" : "=v"(w1) : "a"(pk[x][y][1]));
            #pragma unroll
            for (int r = 0; r < 4; r++) {
              const int row = 64*wave + x*16 + lq*4 + r;
              float v = fmaxf(acc[x][y][r], 0.f);
              v += bf2f((ushort)(((r >> 1) ? w1 : w0) >> (16*(r & 1))));
              if (fl & 4)  v += bf2f(((const ushort*)s.Src2)[(long long)z*s.sS2 + (long long)row*s.ldS2 + col]);
              if (fl & 2)
                ((ushort*)s.O)[(long long)z*s.sO + (long long)row*s.ldc + col] = f2bf(v);
              else
                ((float*)s.O)[(long long)z*s.sO + (long long)row*s.ldc + col] = v;
            }
          }
      }
    } else {
      // ---------------- single branch ----------------
      const ushort* pWf = Wf + (long long)r0 * 512 + c0;
      ISSUE1S(0, 0);
      for (int k0 = 0; k0 < 480; k0 += 32) {
        const int cur = (k0 >> 5) & 1;
        __syncthreads();
        ISSUE1S(k0 + 32, cur ^ 1);
        COMP1S(cur);
      }
      __syncthreads();
      ISSUE2G(0, 0, pGf);
      COMP1S(1);
      DUMPA();
      for (int k0 = 0; k0 < 224; k0 += 32) {
        const int cur = (k0 >> 5) & 1;
        __syncthreads();
        ISSUE2G(k0 + 32, cur ^ 1, pGf);
        COMP2(cur, k0);
      }
      __syncthreads();
      COMP2(1, 224);
      {
        const int fl = s.flags;
        #pragma unroll
        for (int x = 0; x < 4; x++)
          #pragma unroll
          for (int y = 0; y < 4; y++) {
            const int col = n0 + y*16 + lr;
            #pragma unroll
            for (int r = 0; r < 4; r++) {
              const int row = 64*wave + x*16 + lq*4 + r;
              float v = fmaxf(acc[x][y][r], 0.f);
              if (fl & 4)  v += bf2f(((const ushort*)s.Src2)[(long long)z*s.sS2 + (long long)row*s.ldS2 + col]);
              if (fl & 2)
                ((ushort*)s.O)[(long long)z*s.sO + (long long)row*s.ldc + col] = f2bf(v);
              else
                ((float*)s.O)[(long long)z*s.sO + (long long)row*s.ldc + col] = v;
            }
          }
      }
    }
    return;
  }

  if (s.flags & 64) {
    // ================= fused Sc + row softmax =================
    const int niter = s.K >> 5;
    const int z = bid >> 2, mb = bid & 3;
    const ushort* pa = s.A + (long long)z*s.sA + (long long)(mb*64 + (t >> 2))*s.lda + (t & 3)*8;
    const ushort* pb = s.B + (long long)z*s.sB + (long long)(t >> 2)*s.ldb + (t & 3)*8;
    const long long b64 = 64ll*s.ldb;

    f32x4 acc[16] = {};
#define ISSUE_S(idx) { const int _i=(idx); const int _o=(_i&1)*20480 + lb0;      \
    const int _k=_i<<5;                                                          \
    async16(pa + _k, lds, _o);                                                   \
    async16(pb + _k,        lds, _o + 4096);                                     \
    async16(pb + b64 + _k,  lds, _o + 8192);                                     \
    async16(pb + 2*b64 + _k,lds, _o + 12288);                                    \
    async16(pb + 3*b64 + _k,lds, _o + 16384); }
    ISSUE_S(0);
    for (int i = 0; i < niter; ++i) {
      __syncthreads();
      if (i + 1 < niter) ISSUE_S(i + 1);
      const ushort* LA = lds + (i & 1)*10240;
      const ushort* LB = LA + 2048;
      const bf16x8 af = *(const bf16x8*)&LA[(wave*16 + lr)*32 + lq*8];
      #pragma unroll
      for (int j = 0; j < 16; j++) {
        const bf16x8 bfr = *(const bf16x8*)&LB[(j*16 + lr)*32 + lq*8];
        acc[j] = __builtin_amdgcn_mfma_f32_16x16x32_bf16(af, bfr, acc[j], 0, 0, 0);
      }
    }
    float mx[4] = {-1e30f, -1e30f, -1e30f, -1e30f};
    #pragma unroll
    for (int j = 0; j < 16; j++)
      #pragma unroll
      for (int r = 0; r < 4; r++) mx[r] = fmaxf(mx[r], acc[j][r]);
    #pragma unroll
    for (int r = 0; r < 4; r++)
      #pragma unroll
      for (int off = 1; off <= 8; off <<= 1) mx[r] = fmaxf(mx[r], __shfl_xor(mx[r], off, 64));
    float sm[4] = {0.f, 0.f, 0.f, 0.f};
    #pragma unroll
    for (int j = 0; j < 16; j++)
      #pragma unroll
      for (int r = 0; r < 4; r++) { float e = __expf(acc[j][r] - mx[r]); acc[j][r] = e; sm[r] += e; }
    #pragma unroll
    for (int r = 0; r < 4; r++) {
      #pragma unroll
      for (int off = 1; off <= 8; off <<= 1) sm[r] += __shfl_xor(sm[r], off, 64);
      sm[r] = 1.0f / sm[r];
    }
    ushort* Oz = (ushort*)s.O + (long long)z*s.sO;
    #pragma unroll
    for (int j = 0; j < 16; j++)
      #pragma unroll
      for (int r = 0; r < 4; r++) {
        const int row = mb*64 + wave*16 + lq*4 + r;
        Oz[(long long)row*s.ldc + j*16 + lr] = f2bf(acc[j][r]*sm[r]);
      }
    return;
  }

  // ================= plain NT GEMM, double-buffered =================
  {
    // buf b (bytes): lA 128x32 at b*16384, lB 128x32 at b*16384 + 8192
    const int z  = bid / s.nbxy;
    const int rz = bid % s.nbxy;
    const int bx = rz % s.nbx, by = rz / s.nbx;
    const int wm = (wave >> 1)*64, wn = (wave & 1)*64;
    const int r0 = t >> 2, c0 = (t & 3)*8;

    const ushort* pa = s.A + (long long)z*s.sA + (long long)(by*128 + r0)*s.lda + c0;
    const ushort* pb = s.B + (long long)z*s.sB + (long long)(bx*128 + r0)*s.ldb + c0;
    const long long a64 = 64ll*s.lda, b64 = 64ll*s.ldb;

#define ISSUEP(k0s, b) { const int _o = (b)*16384 + lb0;                         \
      async16(pa + (k0s),       lds, _o);                                        \
      async16(pa + a64 + (k0s), lds, _o + 4096);                                 \
      async16(pb + (k0s),       lds, _o + 8192);                                 \
      async16(pb + b64 + (k0s), lds, _o + 12288); }

#define COMPUTEP(curb) {                                                         \
      const ushort* lA = (const ushort*)((const char*)lds + (curb)*16384);       \
      const ushort* lB = lA + 4096;                                              \
      bf16x8 af[4], bfr[4];                                                      \
      _Pragma("unroll") for (int x = 0; x < 4; x++) {                            \
        af[x]  = *(const bf16x8*)&lA[(wm + x*16 + lr)*32 + lq*8];                \
        bfr[x] = *(const bf16x8*)&lB[(wn + x*16 + lr)*32 + lq*8];                \
      }                                                                          \
      MFMA16(af, bfr); }

    f32x4 acc[4][4] = {};
    ISSUEP(0, 0);
    int k0 = 0;
    for (; k0 < s.K - 32; k0 += 32) {
      const int cur = (k0 >> 5) & 1;
      __syncthreads();                 // buf cur ready
      ISSUEP(k0 + 32, cur ^ 1);
      COMPUTEP(cur);
    }
    __syncthreads();
    COMPUTEP((k0 >> 5) & 1);
    const int rowb = by*128 + wm + lq*4;
    const int colb = bx*128 + wn + lr;
    const int fl = s.flags;
    #pragma unroll
    for (int x = 0; x < 4; x++)
      #pragma unroll
      for (int y = 0; y < 4; y++) {
        const int col = colb + y*16;
        #pragma unroll
        for (int r = 0; r < 4; r++) {
          const int row = rowb + x*16 + r;
          float v = acc[x][y][r];
          if (fl & 1) v = fmaxf(v, 0.f);
          if (fl & 2)
            ((ushort*)s.O)[(long long)z*s.sO + (long long)row*s.ldc + col] = f2bf(v);
          else
            ((float*)s.O)[(long long)z*s.sO + (long long)row*s.ldc + col] = v;
        }
      }
  }
}

// ---------------------------------------------------------------------------
// fused prep: [0,8192) cast f -> bf16 ; [8192,11008) 11 weight transposes ;
// [11008,15104) adj -> adj/adjT bf16
// ---------------------------------------------------------------------------
struct P11 { const float* p[11]; };

__global__ void prep(const float* __restrict__ F, ushort* __restrict__ FB,
                     P11 ps, ushort* __restrict__ WT,
                     const float* __restrict__ ADJ, ushort* __restrict__ AB,
                     ushort* __restrict__ ATB)
{
  __shared__ float tile[32][33];
  const int b = blockIdx.x, t = threadIdx.x;
  if (b < 8192) {
    const int i = b*256 + t;
    const float4 v = ((const float4*)F)[i];
    ushort4 o; o.x = f2bf(v.x); o.y = f2bf(v.y); o.z = f2bf(v.z); o.w = f2bf(v.w);
    ((ushort4*)FB)[i] = o;
  } else if (b < 11008) {
    const int q = b - 8192;
    const int wdx = q >> 8, tl = q & 255;
    const int bo = (tl & 15)*32, bk = (tl >> 4)*32;
    const int tx = t & 31, ty = t >> 5;
    const float* in = ps.p[wdx];
    ushort* o = WT + (long long)wdx*262144;
    #pragma unroll
    for (int r = 0; r < 32; r += 8) tile[ty+r][tx] = in[(long long)(bk+ty+r)*512 + bo+tx];
    __syncthreads();
    #pragma unroll
    for (int r = 0; r < 32; r += 8) o[(long long)(bo+ty+r)*512 + bk+tx] = f2bf(tile[tx][ty+r]);
  } else {
    const int q = b - 11008;
    const long long base = (long long)(q >> 6)*65536;
    const int bi = ((q >> 3) & 7)*32, bj = (q & 7)*32;
    const int tx = t & 31, ty = t >> 5;
    #pragma unroll
    for (int r = 0; r < 32; r += 8) {
      const float v = ADJ[base + (long long)(bi+ty+r)*256 + bj+tx];
      tile[ty+r][tx] = v;
      AB[base + (long long)(bi+ty+r)*256 + bj+tx] = f2bf(v);
    }
    __syncthreads();
    #pragma unroll
    for (int r = 0; r < 32; r += 8)
      ATB[base + (long long)(bj+ty+r)*256 + bi+tx] = f2bf(tile[tx][ty+r]);
  }
}

// ---------------------------------------------------------------------------
extern "C" void kernel_launch(void* const* d_in, const int* in_sizes, int n_in,
                              void* d_out, int out_size, void* d_ws, size_t ws_size,
                              hipStream_t stream)
{
  (void)in_sizes; (void)n_in; (void)out_size;
  const float* F   = (const float*)d_in[0];
  const float* ADJ = (const float*)d_in[2];

  uint8_t* w = (uint8_t*)d_ws;
  size_t off = 0;
  auto alloc = [&](size_t bytes) -> void* { void* p = w + off; off += (bytes + 255) & ~(size_t)255; return p; };

  const long long SL = 262144;
  ushort* WT   = (ushort*)alloc(11*524288);  // 0:Wst1 1:Wst1b 2:Wst2 3:Wst2b 4:Wst3 5:Wst3b 6-8:Wsim1-3 9:Wse1T 10:Wse2T
  ushort* WMT  = (ushort*)alloc(524288);
  ushort* FB   = (ushort*)alloc(16777216);
  ushort* ADJB = (ushort*)alloc(8388608);
  ushort* ADJT = (ushort*)alloc(8388608);
  ushort* TB   = (ushort*)alloc(16777216);
  ushort* Sb   = (ushort*)alloc(8388608);
  ushort* Hb   = (ushort*)alloc(16777216);   // st ping
  ushort* Hb2  = (ushort*)alloc(16777216);   // st pong
  ushort* Gb   = (ushort*)alloc(16777216);   // sim ping
  ushort* Gb2  = (ushort*)alloc(16777216);   // sim pong
  if (off > ws_size) return;

  const long long sNC = 131072, sNN = 65536;
  const int LDSB = 81920;   // Yt 32768 + 2x24576 staging dbuf = exactly 2 blocks/CU

  auto zero = [](Seg& s) {
    s.A = nullptr; s.B = nullptr; s.Src = nullptr; s.Src2 = nullptr; s.O = nullptr;
    s.sA = s.sB = s.sS = s.sS2 = s.sO = 0;
    s.lda = s.ldb = s.ldS = s.ldS2 = s.ldc = 0;
    s.K = 0; s.nbx = 1; s.nbxy = 1; s.flags = 0; s.A2off = s.B2off = 0;
  };
  auto mkP = [&](const void* A, long long sA, int lda, const void* B, long long sB, int ldb,
                 void* O, long long sO, int ldc, int K, int M, int Nn, int flags) -> Seg {
    Seg s; zero(s);
    s.A = (const ushort*)A; s.B = (const ushort*)B; s.O = O;
    s.sA = sA; s.sB = sB; s.sO = sO;
    s.lda = lda; s.ldb = ldb; s.ldc = ldc;
    s.K = K; s.nbx = Nn/128; s.nbxy = (Nn/128)*(M/128); s.flags = flags;
    return s;
  };
  auto mkF = [&](const void* X, const void* Wf, long long B2off, const void* G, long long A2off,
                 const void* Src2, void* O, int flags) -> Seg {
    Seg s; zero(s);
    s.A = (const ushort*)X; s.sA = sNC; s.lda = 512;
    s.B = (const ushort*)Wf; s.B2off = B2off;
    s.Src = G; s.sS = sNN; s.ldS = 256; s.A2off = A2off;
    s.Src2 = Src2; s.sS2 = sNC; s.ldS2 = 512;
    s.O = O; s.sO = sNC; s.ldc = 512;
    s.flags = 128 | flags;
    return s;
  };
  auto L1 = [&](const Seg& a, int na) { mega<<<na, 256, LDSB, stream>>>(a, a, a, na, na); };
  // heavy-first packing: the large segment occupies bid 0..na-1 so the small
  // partner fills the dispatch tail (bid-rebase logic is split-agnostic).
  auto L2 = [&](const Seg& a, int na, const Seg& b, int nb) {
    mega<<<na+nb, 256, LDSB, stream>>>(a, b, b, na, na+nb); };

  // ---- D1: fused prep ----
  P11 ps;
  ps.p[0] = (const float*)d_in[5];  ps.p[1] = (const float*)d_in[8];
  ps.p[2] = (const float*)d_in[6];  ps.p[3] = (const float*)d_in[9];
  ps.p[4] = (const float*)d_in[7];  ps.p[5] = (const float*)d_in[10];
  ps.p[6] = (const float*)d_in[11]; ps.p[7] = (const float*)d_in[12];
  ps.p[8] = (const float*)d_in[13];
  ps.p[9] = (const float*)d_in[3];  ps.p[10] = (const float*)d_in[4];
  prep<<<15104, 256, 0, stream>>>(F, FB, ps, WT, ADJ, ADJB, ADJT);

  const long long dA = (long long)(ADJT - ADJB);

  Seg Wmid = mkP(WT+10*SL,0,512, WT+9*SL,0,512, WMT,0,512, 512, 512,512, 2);
  Seg Tsg  = mkP(FB,sNC,512, WMT,0,512, TB,sNC,512, 512, 256,512, 2);
  Seg ScS; zero(ScS);
  ScS.A = TB; ScS.B = FB; ScS.O = Sb;
  ScS.sA = sNC; ScS.sB = sNC; ScS.sO = sNN;
  ScS.lda = 512; ScS.ldb = 512; ScS.ldc = 256;
  ScS.K = 512; ScS.flags = 64;

  Seg ST1  = mkF(FB,  WT+0*SL, SL, ADJB, dA, nullptr, Hb,  16|2);
  Seg ST2  = mkF(Hb,  WT+2*SL, SL, ADJB, dA, nullptr, Hb2, 16|2);
  Seg ST3  = mkF(Hb2, WT+4*SL, SL, ADJB, dA, nullptr, Hb,  16|2);
  Seg SIM1 = mkF(FB,  WT+6*SL, 0,  Sb,   0,  nullptr, Gb,  2);
  Seg SIM2 = mkF(Gb,  WT+7*SL, 0,  Sb,   0,  nullptr, Gb2, 2);
  Seg SIM3 = mkF(Gb2, WT+8*SL, 0,  Sb,   0,  Hb,      d_out, 4);   // fp32 out = relu(S@Y3) + Hst

  // ---- schedule: st chain || sim front-end (heavy segment first) ----
  L2(ST1,512, Wmid,16);   // D2
  L2(ST2,512, Tsg,512);   // D3
  L2(ST3,512, ScS,256);   // D4
  L1(SIM1,512);           // D5
  L1(SIM2,512);           // D6
  L1(SIM3,512);           // D7
}